// Round 8
// baseline (309.197 us; speedup 1.0000x reference)
//
#include <hip/hip_runtime.h>
#include <hip/hip_bf16.h>

#define HDIM 128

typedef short bf16x8 __attribute__((ext_vector_type(8)));
typedef float f32x4 __attribute__((ext_vector_type(4)));
typedef int   i32x4 __attribute__((ext_vector_type(4)));

__device__ __forceinline__ short f2bf(float f) {
    __hip_bfloat16 h = __float2bfloat16(f);
    return __builtin_bit_cast(short, h);
}

__device__ __forceinline__ float bf2f(short s) {
    unsigned u = ((unsigned)(unsigned short)s) << 16;
    return __builtin_bit_cast(float, u);
}

// B-fragment read from swizzled WT[n][k] LDS image
__device__ __forceinline__ bf16x8 ldB(const short* sW, int n, int chunk) {
    return *(const bf16x8*)(sW + n * HDIM + ((chunk ^ (n & 7)) << 3));
}

__device__ __forceinline__ bf16x8 gatherA_f32(const float* xs, const float* xd, int k0) {
    float4 a0 = *(const float4*)(xs + k0);
    float4 a1 = *(const float4*)(xs + k0 + 4);
    float4 c0 = *(const float4*)(xd + k0);
    float4 c1 = *(const float4*)(xd + k0 + 4);
    bf16x8 r = { f2bf(a0.x * c0.x), f2bf(a0.y * c0.y), f2bf(a0.z * c0.z), f2bf(a0.w * c0.w),
                 f2bf(a1.x * c1.x), f2bf(a1.y * c1.y), f2bf(a1.z * c1.z), f2bf(a1.w * c1.w) };
    return r;
}

__global__ void cvt_kernel(const float* __restrict__ x, unsigned short* __restrict__ xb, int n4) {
    int i = blockIdx.x * blockDim.x + threadIdx.x;
    const int stride = gridDim.x * blockDim.x;
    for (; i < n4; i += stride) {
        float4 v = ((const float4*)x)[i];
        ushort4 o;
        o.x = (unsigned short)f2bf(v.x);
        o.y = (unsigned short)f2bf(v.y);
        o.z = (unsigned short)f2bf(v.z);
        o.w = (unsigned short)f2bf(v.w);
        ((ushort4*)xb)[i] = o;
    }
}

// 512 threads = 8 waves x 16 edges -> 128-edge block tile.
// LDS: 64 KB weights + 8x8 KB coalesced row staging + 8x2 KB H1 staging = 144 KB -> 1 block/CU.
// Gathers are COALESCED: one dwordx4 instr reads 4 full 256B rows (16 contiguous lanes/row)
// = 8 dense 128B lines, vs 64 scattered 16B requests in the divergent formulation.
template<bool XBF>
__global__ __launch_bounds__(512, 1)
void edge_mlp_kernel(const float* __restrict__ x,
                     const unsigned short* __restrict__ xb,
                     const int* __restrict__ src,
                     const int* __restrict__ dst,
                     const float* __restrict__ W1, const float* __restrict__ b1,
                     const float* __restrict__ W2, const float* __restrict__ b2,
                     const float* __restrict__ W3, const float* __restrict__ b3,
                     float* __restrict__ out, int E, int ntiles)
{
    __shared__ short sW1[HDIM * HDIM];     // 32 KB
    __shared__ short sW2[HDIM * HDIM];     // 32 KB
    __shared__ short sStage[8][4096];      // 64 KB: per-wave [q][row][chunk^] (2x16x16 chunks of 16B)
    __shared__ short sH1[8][16 * 64];      // 16 KB

    const int tid = threadIdx.x;

    // ---- stage weights fp32 [k][n] -> LDS bf16 WT[n][k], swizzled ----
    {
        const int n  = tid & 127;
        const int kh = tid >> 7;            // 0..3
        #pragma unroll
        for (int c = 0; c < 4; ++c) {
            const int kc = kh * 4 + c;
            const int k0 = kc * 8;
            short v1[8], v2[8];
            #pragma unroll
            for (int j = 0; j < 8; ++j) {
                v1[j] = f2bf(W1[(k0 + j) * HDIM + n]);
                v2[j] = f2bf(W2[(k0 + j) * HDIM + n]);
            }
            const int off = n * HDIM + ((kc ^ (n & 7)) << 3);
            bf16x8 t1 = { v1[0], v1[1], v1[2], v1[3], v1[4], v1[5], v1[6], v1[7] };
            bf16x8 t2 = { v2[0], v2[1], v2[2], v2[3], v2[4], v2[5], v2[6], v2[7] };
            *(bf16x8*)(sW1 + off) = t1;
            *(bf16x8*)(sW2 + off) = t2;
        }
    }
    __syncthreads();   // only barrier; everything else is wave-private

    const int w    = tid >> 6;      // wave 0..7
    const int lane = tid & 63;
    const int g    = lane >> 4;     // 16-lane group 0..3
    const int e16  = lane & 15;
    short* myH1 = &sH1[w][0];
    short* myS  = &sStage[w][0];
    const int lhi = lane >> 4;      // which row within a 4-row load instr
    const int c16 = lane & 15;      // 16B chunk within row

    float b1v[8], b2v[8], w3v[8];
    #pragma unroll
    for (int nt = 0; nt < 8; ++nt) {
        b1v[nt] = b1[nt * 16 + e16];
        b2v[nt] = b2[nt * 16 + e16];
        w3v[nt] = W3[nt * 16 + e16];
    }
    const float b3s = b3[0];

    const int G = gridDim.x;
    int tile = blockIdx.x;
    if (tile >= ntiles) return;

    // ---- current tile ids ----
    int s0, d0;
    {
        const int base = (tile << 7) + (w << 4);
        int a0 = base + e16;  a0 = a0 < E ? a0 : 0;
        s0 = src[a0]; d0 = dst[a0];
    }

    i32x4 P[8];   // in-flight coalesced rows (32 VGPR)
    if constexpr (XBF) {
        // prologue: load + stage current tile's 32 rows
        #pragma unroll
        for (int i = 0; i < 8; ++i) {
            const int idr = (i < 4) ? s0 : d0;
            const int jr  = ((i & 3) << 2) + lhi;
            const int rid = __builtin_amdgcn_ds_bpermute(jr << 2, idr);
            const int* p = (const int*)(xb + (size_t)rid * HDIM) + (c16 << 2);
            P[i] = *(const i32x4*)p;
        }
        #pragma unroll
        for (int i = 0; i < 8; ++i) {
            const int q  = i >> 2;
            const int j0 = ((i & 3) << 2) + lhi;
            *(i32x4*)(myS + q * 2048 + j0 * 128 + ((c16 ^ j0) << 3)) = P[i];
        }
    }

    // next-tile ids
    int sN = 0, dN = 0;
    {
        const bool hn = tile + G < ntiles;
        const int nb = hn ? ((tile + G) << 7) + (w << 4) : 0;
        int a0 = nb + e16;  a0 = a0 < E ? a0 : 0;
        sN = src[a0]; dN = dst[a0];
    }

    for (;;) {
        const bool hasN = tile + G < ntiles;

        // issue next tile's coalesced row loads (land during GEMM1+GEMM2)
        if constexpr (XBF) {
            if (hasN) {
                #pragma unroll
                for (int i = 0; i < 8; ++i) {
                    const int idr = (i < 4) ? sN : dN;
                    const int jr  = ((i & 3) << 2) + lhi;
                    const int rid = __builtin_amdgcn_ds_bpermute(jr << 2, idr);
                    const int* p = (const int*)(xb + (size_t)rid * HDIM) + (c16 << 2);
                    P[i] = *(const i32x4*)p;
                }
            }
        }
        // prefetch ids two tiles ahead
        int sN2 = 0, dN2 = 0;
        {
            const bool hn2 = tile + 2 * G < ntiles;
            const int nb = hn2 ? ((tile + 2 * G) << 7) + (w << 4) : 0;
            int a0 = nb + e16;  a0 = a0 < E ? a0 : 0;
            sN2 = src[a0]; dN2 = dst[a0];
        }

        const int base = (tile << 7) + (w << 4);

        // ---------- GEMM1: H1 = relu((xs*xd) @ W1 + b1) ----------
        f32x4 acc[8];
        #pragma unroll
        for (int nt = 0; nt < 8; ++nt) {
            f32x4 iv = { b1v[nt], b1v[nt], b1v[nt], b1v[nt] };
            acc[nt] = iv;
        }

        if constexpr (XBF) {
            #pragma unroll
            for (int t = 0; t < 4; ++t) {
                const int co = (((t << 2) + g) ^ e16) << 3;
                bf16x8 vs = *(const bf16x8*)(myS + e16 * 128 + co);
                bf16x8 vd = *(const bf16x8*)(myS + 2048 + e16 * 128 + co);
                bf16x8 a0;
                #pragma unroll
                for (int j = 0; j < 8; ++j)
                    a0[j] = f2bf(bf2f(vs[j]) * bf2f(vd[j]));
                #pragma unroll
                for (int nt = 0; nt < 8; ++nt) {
                    bf16x8 bb = ldB(sW1, nt * 16 + e16, t * 4 + g);
                    acc[nt] = __builtin_amdgcn_mfma_f32_16x16x32_bf16(a0, bb, acc[nt], 0, 0, 0);
                }
            }
        } else {
            const float* xs0 = x + (size_t)s0 * HDIM;
            const float* xd0 = x + (size_t)d0 * HDIM;
            #pragma unroll
            for (int t = 0; t < 4; ++t) {
                const int k0 = t * 32 + g * 8;
                bf16x8 a0 = gatherA_f32(xs0, xd0, k0);
                #pragma unroll
                for (int nt = 0; nt < 8; ++nt) {
                    bf16x8 bb = ldB(sW1, nt * 16 + e16, t * 4 + g);
                    acc[nt] = __builtin_amdgcn_mfma_f32_16x16x32_bf16(a0, bb, acc[nt], 0, 0, 0);
                }
            }
        }

        // ---------- GEMM2: H2 = relu(H1 @ W2 + b2) ----------
        f32x4 acc2[8];
        #pragma unroll
        for (int nt = 0; nt < 8; ++nt) {
            f32x4 iv = { b2v[nt], b2v[nt], b2v[nt], b2v[nt] };
            acc2[nt] = iv;
        }
        #pragma unroll
        for (int khf = 0; khf < 2; ++khf) {
            #pragma unroll
            for (int ntl = 0; ntl < 4; ++ntl) {
                const int nt = khf * 4 + ntl;
                #pragma unroll
                for (int r = 0; r < 4; ++r) {
                    const int e  = g * 4 + r;
                    const int kk = ntl * 16 + e16;
                    float v = acc[nt][r];
                    v = v > 0.0f ? v : 0.0f;
                    myH1[e * 64 + (((kk >> 3) ^ (e & 7)) << 3) + (kk & 7)] = f2bf(v);
                }
            }
            #pragma unroll
            for (int tl = 0; tl < 2; ++tl) {
                const int ck = tl * 4 + g;
                bf16x8 a0 = *(const bf16x8*)(myH1 + e16 * 64 + ((ck ^ (e16 & 7)) << 3));
                const int t2 = khf * 2 + tl;
                #pragma unroll
                for (int nt = 0; nt < 8; ++nt) {
                    bf16x8 bb = ldB(sW2, nt * 16 + e16, t2 * 4 + g);
                    acc2[nt] = __builtin_amdgcn_mfma_f32_16x16x32_bf16(a0, bb, acc2[nt], 0, 0, 0);
                }
            }
        }

        // ---------- stage next tile's rows (loads had GEMM1+GEMM2 to land) ----------
        if constexpr (XBF) {
            if (hasN) {
                #pragma unroll
                for (int i = 0; i < 8; ++i) {
                    const int q  = i >> 2;
                    const int j0 = ((i & 3) << 2) + lhi;
                    *(i32x4*)(myS + q * 2048 + j0 * 128 + ((c16 ^ j0) << 3)) = P[i];
                }
            }
        }

        // ---------- final: out = relu(H2) @ W3 + b3, 16-lane butterfly ----------
        {
            float p0 = 0.f, p1 = 0.f, p2 = 0.f, p3 = 0.f;
            #pragma unroll
            for (int nt = 0; nt < 8; ++nt) {
                f32x4 v = acc2[nt];
                float r0 = v[0] > 0.f ? v[0] : 0.f;
                float r1 = v[1] > 0.f ? v[1] : 0.f;
                float r2 = v[2] > 0.f ? v[2] : 0.f;
                float r3 = v[3] > 0.f ? v[3] : 0.f;
                p0 += r0 * w3v[nt];
                p1 += r1 * w3v[nt];
                p2 += r2 * w3v[nt];
                p3 += r3 * w3v[nt];
            }
            #pragma unroll
            for (int off = 1; off < 16; off <<= 1) {
                p0 += __shfl_xor(p0, off);
                p1 += __shfl_xor(p1, off);
                p2 += __shfl_xor(p2, off);
                p3 += __shfl_xor(p3, off);
            }
            if (e16 == 0) {
                const int eb = base + g * 4;
                if (eb + 0 < E) out[eb + 0] = p0 + b3s;
                if (eb + 1 < E) out[eb + 1] = p1 + b3s;
                if (eb + 2 < E) out[eb + 2] = p2 + b3s;
                if (eb + 3 < E) out[eb + 3] = p3 + b3s;
            }
        }

        if (!hasN) break;
        tile += G;
        s0 = sN; d0 = dN;
        sN = sN2; dN = dN2;
    }
}

extern "C" void kernel_launch(void* const* d_in, const int* in_sizes, int n_in,
                              void* d_out, int out_size, void* d_ws, size_t ws_size,
                              hipStream_t stream) {
    const float* x   = (const float*)d_in[0];
    const int*   src = (const int*)d_in[1];
    const int*   dst = (const int*)d_in[2];
    const float* W1  = (const float*)d_in[3];
    const float* b1  = (const float*)d_in[4];
    const float* W2  = (const float*)d_in[5];
    const float* b2  = (const float*)d_in[6];
    const float* W3  = (const float*)d_in[7];
    const float* b3  = (const float*)d_in[8];
    float* out = (float*)d_out;

    const int xelems = in_sizes[0];           // N_NODES * 128
    const int E = in_sizes[1];
    const int ntiles = (E + 127) >> 7;        // 128 edges per block-tile (8 waves x 16)
    const int grid = ntiles < 256 ? ntiles : 256;   // 1 block/CU

    const size_t need = (size_t)xelems * sizeof(unsigned short);
    if (ws_size >= need) {
        unsigned short* xb = (unsigned short*)d_ws;
        hipLaunchKernelGGL(cvt_kernel, dim3(2048), dim3(256), 0, stream, x, xb, xelems >> 2);
        hipLaunchKernelGGL((edge_mlp_kernel<true>), dim3(grid), dim3(512), 0, stream,
                           x, xb, src, dst, W1, b1, W2, b2, W3, b3, out, E, ntiles);
    } else {
        hipLaunchKernelGGL((edge_mlp_kernel<false>), dim3(grid), dim3(512), 0, stream,
                           x, (const unsigned short*)nullptr, src, dst,
                           W1, b1, W2, b2, W3, b3, out, E, ntiles);
    }
}

// Round 9
// 121.292 us; speedup vs baseline: 2.5492x; 2.5492x over previous
//
#include <hip/hip_runtime.h>
#include <hip/hip_bf16.h>

#define HDIM 128

typedef short bf16x8 __attribute__((ext_vector_type(8)));
typedef float f32x4 __attribute__((ext_vector_type(4)));

__device__ __forceinline__ short f2bf(float f) {
    __hip_bfloat16 h = __float2bfloat16(f);
    return __builtin_bit_cast(short, h);
}

__device__ __forceinline__ float bf2f(short s) {
    unsigned u = ((unsigned)(unsigned short)s) << 16;
    return __builtin_bit_cast(float, u);
}

// B-fragment read from swizzled WT[n][k] LDS image
__device__ __forceinline__ bf16x8 ldB(const short* sW, int n, int chunk) {
    return *(const bf16x8*)(sW + n * HDIM + ((chunk ^ (n & 7)) << 3));
}

// async global->LDS, 16B per lane, LDS dest = uniform base + lane*16
__device__ __forceinline__ void dma16(const void* g, void* l) {
    __builtin_amdgcn_global_load_lds(
        (const __attribute__((address_space(1))) void*)g,
        (__attribute__((address_space(3))) void*)l, 16, 0, 0);
}

__device__ __forceinline__ bf16x8 gatherA_f32(const float* xs, const float* xd, int k0) {
    float4 a0 = *(const float4*)(xs + k0);
    float4 a1 = *(const float4*)(xs + k0 + 4);
    float4 c0 = *(const float4*)(xd + k0);
    float4 c1 = *(const float4*)(xd + k0 + 4);
    bf16x8 r = { f2bf(a0.x * c0.x), f2bf(a0.y * c0.y), f2bf(a0.z * c0.z), f2bf(a0.w * c0.w),
                 f2bf(a1.x * c1.x), f2bf(a1.y * c1.y), f2bf(a1.z * c1.z), f2bf(a1.w * c1.w) };
    return r;
}

__global__ void cvt_kernel(const float* __restrict__ x, unsigned short* __restrict__ xb, int n4) {
    int i = blockIdx.x * blockDim.x + threadIdx.x;
    const int stride = gridDim.x * blockDim.x;
    for (; i < n4; i += stride) {
        float4 v = ((const float4*)x)[i];
        ushort4 o;
        o.x = (unsigned short)f2bf(v.x);
        o.y = (unsigned short)f2bf(v.y);
        o.z = (unsigned short)f2bf(v.z);
        o.w = (unsigned short)f2bf(v.w);
        ((ushort4*)xb)[i] = o;
    }
}

// 256 threads = 4 waves x 32 edges -> 128-edge tile.
// LDS: 64 KB weights + 4 x 16 KB coalesced row stage (DMA'd) + 16 KB sH1 = 144 KB -> 1 block/CU.
// Gather: one global_load_lds reads 4 complete 256B rows (16 contiguous lanes/row)
// = 8 dense 128B lines/instr, vs 64 scattered 16B requests in the divergent form.
template<bool XBF>
__global__ __launch_bounds__(256, 2)
void edge_mlp_kernel(const float* __restrict__ x,
                     const unsigned short* __restrict__ xb,
                     const int* __restrict__ src,
                     const int* __restrict__ dst,
                     const float* __restrict__ W1, const float* __restrict__ b1,
                     const float* __restrict__ W2, const float* __restrict__ b2,
                     const float* __restrict__ W3, const float* __restrict__ b3,
                     float* __restrict__ out, int E, int ntiles)
{
    __shared__ short sW1[HDIM * HDIM];      // 32 KB
    __shared__ short sW2[HDIM * HDIM];      // 32 KB
    __shared__ short sStage[4][64 * 128];   // 64 KB: per-wave 64 rows (32 src + 32 dst) x 256 B
    __shared__ short sH1[4][32 * 64];       // 16 KB

    const int tid = threadIdx.x;

    // ---- stage weights fp32 [k][n] -> LDS bf16 WT[n][k], swizzled ----
    {
        const int n  = tid & 127;
        const int kh = tid >> 7;            // 0 or 1
        for (int c = 0; c < 8; ++c) {
            const int kc = kh * 8 + c;      // 16B chunk index, 0..15
            const int k0 = kc * 8;
            short v1[8], v2[8];
            #pragma unroll
            for (int j = 0; j < 8; ++j) {
                v1[j] = f2bf(W1[(k0 + j) * HDIM + n]);
                v2[j] = f2bf(W2[(k0 + j) * HDIM + n]);
            }
            const int off = n * HDIM + ((kc ^ (n & 7)) << 3);
            bf16x8 t1 = { v1[0], v1[1], v1[2], v1[3], v1[4], v1[5], v1[6], v1[7] };
            bf16x8 t2 = { v2[0], v2[1], v2[2], v2[3], v2[4], v2[5], v2[6], v2[7] };
            *(bf16x8*)(sW1 + off) = t1;
            *(bf16x8*)(sW2 + off) = t2;
        }
    }
    __syncthreads();   // only barrier; stage/sH1 are wave-private

    const int w     = tid >> 6;     // wave 0..3
    const int lane  = tid & 63;
    const int g     = lane >> 4;    // 16-lane group 0..3
    const int e16   = lane & 15;
    const int elane = lane & 31;
    short* myH1 = &sH1[w][0];
    short* myS  = &sStage[w][0];

    float b1v[8], b2v[8], w3v[8];
    #pragma unroll
    for (int nt = 0; nt < 8; ++nt) {
        b1v[nt] = b1[nt * 16 + e16];
        b2v[nt] = b2[nt * 16 + e16];
        w3v[nt] = W3[nt * 16 + e16];
    }
    const float b3s = b3[0];

    const int G = gridDim.x;
    int tile = blockIdx.x;
    if (tile >= ntiles) return;

    // idv: lane<32 holds src id of edge (base+lane), lane>=32 holds dst id of edge (base+lane-32)
    #define LOAD_IDS(T, OUTV) {                                   \
        int a = ((T) << 7) + (w << 5) + elane;                    \
        a = a < E ? a : 0;                                        \
        (OUTV) = (lane < 32) ? src[a] : dst[a];                   \
    }

    // 16 coalesced DMAs: instr i loads 4 rows (i<8: src edges 4i..4i+3, i>=8: dst)
    // global chunk pre-swizzled (c16 ^ (edge&7)) so the XOR'd read below is correct.
    #define ISSUE_DMA(IDV) {                                      \
        _Pragma("unroll")                                         \
        for (int i = 0; i < 16; ++i) {                            \
            const int e4 = (i & 7) * 4 + (lane >> 4);             \
            const int rowlane = (i < 8) ? e4 : (32 + e4);         \
            const int rid = __builtin_amdgcn_ds_bpermute(rowlane << 2, (IDV)); \
            const int gchunk = (lane & 15) ^ (e4 & 7);            \
            dma16(xb + (size_t)rid * HDIM + (gchunk << 3), myS + i * 512); \
        }                                                         \
    }

    int idv;
    LOAD_IDS(tile, idv);
    if constexpr (XBF) { ISSUE_DMA(idv); }
    int idvN = 0;
    if (tile + G < ntiles) LOAD_IDS(tile + G, idvN);

    for (;;) {
        const bool hasN = tile + G < ntiles;
        const int base = (tile << 7) + (w << 5);

        // ---------- GEMM1: H1 = relu((xs*xd) @ W1 + b1) ----------
        f32x4 acc[2][8];
        #pragma unroll
        for (int nt = 0; nt < 8; ++nt) {
            f32x4 iv = { b1v[nt], b1v[nt], b1v[nt], b1v[nt] };
            acc[0][nt] = iv;
            acc[1][nt] = iv;
        }

        if constexpr (XBF) {
            asm volatile("s_waitcnt vmcnt(0)" ::: "memory");   // this tile's DMA landed
            #pragma unroll
            for (int t = 0; t < 4; ++t) {
                const int c0 = (((t << 2) + g) ^ (e16 & 7)) << 3;
                bf16x8 vs0 = *(const bf16x8*)(myS + e16 * 128 + c0);
                bf16x8 vd0 = *(const bf16x8*)(myS + 4096 + e16 * 128 + c0);
                bf16x8 vs1 = *(const bf16x8*)(myS + (16 + e16) * 128 + c0);
                bf16x8 vd1 = *(const bf16x8*)(myS + 4096 + (16 + e16) * 128 + c0);
                bf16x8 a0, a1;
                #pragma unroll
                for (int j = 0; j < 8; ++j) {
                    a0[j] = f2bf(bf2f(vs0[j]) * bf2f(vd0[j]));
                    a1[j] = f2bf(bf2f(vs1[j]) * bf2f(vd1[j]));
                }
                #pragma unroll
                for (int nt = 0; nt < 8; ++nt) {
                    bf16x8 bb = ldB(sW1, nt * 16 + e16, t * 4 + g);
                    acc[0][nt] = __builtin_amdgcn_mfma_f32_16x16x32_bf16(a0, bb, acc[0][nt], 0, 0, 0);
                    acc[1][nt] = __builtin_amdgcn_mfma_f32_16x16x32_bf16(a1, bb, acc[1][nt], 0, 0, 0);
                }
            }
        } else {
            const int s0 = __builtin_amdgcn_ds_bpermute(e16 << 2, idv);
            const int d0 = __builtin_amdgcn_ds_bpermute((32 + e16) << 2, idv);
            const int s1 = __builtin_amdgcn_ds_bpermute((16 + e16) << 2, idv);
            const int d1 = __builtin_amdgcn_ds_bpermute((48 + e16) << 2, idv);
            const float* xs0 = x + (size_t)s0 * HDIM;
            const float* xd0 = x + (size_t)d0 * HDIM;
            const float* xs1 = x + (size_t)s1 * HDIM;
            const float* xd1 = x + (size_t)d1 * HDIM;
            #pragma unroll
            for (int t = 0; t < 4; ++t) {
                const int k0 = t * 32 + g * 8;
                bf16x8 a0 = gatherA_f32(xs0, xd0, k0);
                bf16x8 a1 = gatherA_f32(xs1, xd1, k0);
                #pragma unroll
                for (int nt = 0; nt < 8; ++nt) {
                    bf16x8 bb = ldB(sW1, nt * 16 + e16, t * 4 + g);
                    acc[0][nt] = __builtin_amdgcn_mfma_f32_16x16x32_bf16(a0, bb, acc[0][nt], 0, 0, 0);
                    acc[1][nt] = __builtin_amdgcn_mfma_f32_16x16x32_bf16(a1, bb, acc[1][nt], 0, 0, 0);
                }
            }
        }

        // ---------- stage is free: issue next tile's DMA (lands under GEMM2+epilogue) ----------
        if constexpr (XBF) {
            if (hasN) {
                asm volatile("s_waitcnt lgkmcnt(0)" ::: "memory");  // stage reads drained
                ISSUE_DMA(idvN);
            }
        }
        int idvN2 = 0;
        if (tile + 2 * G < ntiles) LOAD_IDS(tile + 2 * G, idvN2);

        // ---------- GEMM2: H2 = relu(H1 @ W2 + b2) ----------
        f32x4 acc2[2][8];
        #pragma unroll
        for (int nt = 0; nt < 8; ++nt) {
            f32x4 iv = { b2v[nt], b2v[nt], b2v[nt], b2v[nt] };
            acc2[0][nt] = iv;
            acc2[1][nt] = iv;
        }
        #pragma unroll
        for (int khf = 0; khf < 2; ++khf) {
            #pragma unroll
            for (int ntl = 0; ntl < 4; ++ntl) {
                const int nt = khf * 4 + ntl;
                #pragma unroll
                for (int mt = 0; mt < 2; ++mt) {
                    #pragma unroll
                    for (int r = 0; r < 4; ++r) {
                        const int e  = mt * 16 + g * 4 + r;
                        const int kk = ntl * 16 + e16;
                        float v = acc[mt][nt][r];
                        v = v > 0.0f ? v : 0.0f;
                        myH1[e * 64 + (((kk >> 3) ^ (e & 7)) << 3) + (kk & 7)] = f2bf(v);
                    }
                }
            }
            #pragma unroll
            for (int tl = 0; tl < 2; ++tl) {
                const int ck = tl * 4 + g;
                bf16x8 a0 = *(const bf16x8*)(myH1 + e16 * 64 + ((ck ^ (e16 & 7)) << 3));
                bf16x8 a1 = *(const bf16x8*)(myH1 + (e16 + 16) * 64 + ((ck ^ ((e16 + 16) & 7)) << 3));
                const int t2 = khf * 2 + tl;
                #pragma unroll
                for (int nt = 0; nt < 8; ++nt) {
                    bf16x8 bb = ldB(sW2, nt * 16 + e16, t2 * 4 + g);
                    acc2[0][nt] = __builtin_amdgcn_mfma_f32_16x16x32_bf16(a0, bb, acc2[0][nt], 0, 0, 0);
                    acc2[1][nt] = __builtin_amdgcn_mfma_f32_16x16x32_bf16(a1, bb, acc2[1][nt], 0, 0, 0);
                }
            }
        }

        // ---------- final: out = relu(H2) @ W3 + b3, 16-lane butterfly ----------
        #pragma unroll
        for (int mt = 0; mt < 2; ++mt) {
            float p0 = 0.f, p1 = 0.f, p2 = 0.f, p3 = 0.f;
            #pragma unroll
            for (int nt = 0; nt < 8; ++nt) {
                f32x4 v = acc2[mt][nt];
                float r0 = v[0] > 0.f ? v[0] : 0.f;
                float r1 = v[1] > 0.f ? v[1] : 0.f;
                float r2 = v[2] > 0.f ? v[2] : 0.f;
                float r3 = v[3] > 0.f ? v[3] : 0.f;
                p0 += r0 * w3v[nt];
                p1 += r1 * w3v[nt];
                p2 += r2 * w3v[nt];
                p3 += r3 * w3v[nt];
            }
            #pragma unroll
            for (int off = 1; off < 16; off <<= 1) {
                p0 += __shfl_xor(p0, off);
                p1 += __shfl_xor(p1, off);
                p2 += __shfl_xor(p2, off);
                p3 += __shfl_xor(p3, off);
            }
            if (e16 == 0) {
                const int eb = base + mt * 16 + g * 4;
                if (eb + 0 < E) out[eb + 0] = p0 + b3s;
                if (eb + 1 < E) out[eb + 1] = p1 + b3s;
                if (eb + 2 < E) out[eb + 2] = p2 + b3s;
                if (eb + 3 < E) out[eb + 3] = p3 + b3s;
            }
        }

        if (!hasN) break;
        tile += G;
        idv = idvN;
        idvN = idvN2;
    }
    #undef LOAD_IDS
    #undef ISSUE_DMA
}

extern "C" void kernel_launch(void* const* d_in, const int* in_sizes, int n_in,
                              void* d_out, int out_size, void* d_ws, size_t ws_size,
                              hipStream_t stream) {
    const float* x   = (const float*)d_in[0];
    const int*   src = (const int*)d_in[1];
    const int*   dst = (const int*)d_in[2];
    const float* W1  = (const float*)d_in[3];
    const float* b1  = (const float*)d_in[4];
    const float* W2  = (const float*)d_in[5];
    const float* b2  = (const float*)d_in[6];
    const float* W3  = (const float*)d_in[7];
    const float* b3  = (const float*)d_in[8];
    float* out = (float*)d_out;

    const int xelems = in_sizes[0];           // N_NODES * 128
    const int E = in_sizes[1];
    const int ntiles = (E + 127) >> 7;        // 128 edges per block-tile (4 waves x 32)
    const int grid = ntiles < 256 ? ntiles : 256;   // 1 block/CU (144 KB LDS)

    const size_t need = (size_t)xelems * sizeof(unsigned short);
    if (ws_size >= need) {
        unsigned short* xb = (unsigned short*)d_ws;
        hipLaunchKernelGGL(cvt_kernel, dim3(2048), dim3(256), 0, stream, x, xb, xelems >> 2);
        hipLaunchKernelGGL((edge_mlp_kernel<true>), dim3(grid), dim3(256), 0, stream,
                           x, xb, src, dst, W1, b1, W2, b2, W3, b3, out, E, ntiles);
    } else {
        hipLaunchKernelGGL((edge_mlp_kernel<false>), dim3(grid), dim3(256), 0, stream,
                           x, (const unsigned short*)nullptr, src, dst,
                           W1, b1, W2, b2, W3, b3, out, E, ntiles);
    }
}

// Round 10
// 96.991 us; speedup vs baseline: 3.1879x; 1.2505x over previous
//
#include <hip/hip_runtime.h>
#include <hip/hip_bf16.h>

#define HDIM 128

typedef short bf16x8 __attribute__((ext_vector_type(8)));
typedef float f32x4 __attribute__((ext_vector_type(4)));

__device__ __forceinline__ short f2bf(float f) {
    __hip_bfloat16 h = __float2bfloat16(f);
    return __builtin_bit_cast(short, h);
}

__device__ __forceinline__ float bf2f(short s) {
    unsigned u = ((unsigned)(unsigned short)s) << 16;
    return __builtin_bit_cast(float, u);
}

// B-fragment read from swizzled WT[n][k] LDS image
__device__ __forceinline__ bf16x8 ldB(const short* sW, int n, int chunk) {
    return *(const bf16x8*)(sW + n * HDIM + ((chunk ^ (n & 7)) << 3));
}

// async global->LDS, 16B per lane, LDS dest = uniform base + lane*16
__device__ __forceinline__ void dma16(const void* g, void* l) {
    __builtin_amdgcn_global_load_lds(
        (const __attribute__((address_space(1))) void*)g,
        (__attribute__((address_space(3))) void*)l, 16, 0, 0);
}

__device__ __forceinline__ bf16x8 gatherA_f32(const float* xs, const float* xd, int k0) {
    float4 a0 = *(const float4*)(xs + k0);
    float4 a1 = *(const float4*)(xs + k0 + 4);
    float4 c0 = *(const float4*)(xd + k0);
    float4 c1 = *(const float4*)(xd + k0 + 4);
    bf16x8 r = { f2bf(a0.x * c0.x), f2bf(a0.y * c0.y), f2bf(a0.z * c0.z), f2bf(a0.w * c0.w),
                 f2bf(a1.x * c1.x), f2bf(a1.y * c1.y), f2bf(a1.z * c1.z), f2bf(a1.w * c1.w) };
    return r;
}

__global__ void cvt_kernel(const float* __restrict__ x, unsigned short* __restrict__ xb, int n4) {
    int i = blockIdx.x * blockDim.x + threadIdx.x;
    const int stride = gridDim.x * blockDim.x;
    for (; i < n4; i += stride) {
        float4 v = ((const float4*)x)[i];
        ushort4 o;
        o.x = (unsigned short)f2bf(v.x);
        o.y = (unsigned short)f2bf(v.y);
        o.z = (unsigned short)f2bf(v.z);
        o.w = (unsigned short)f2bf(v.w);
        ((ushort4*)xb)[i] = o;
    }
}

// 512 threads = 8 waves x 16 edges -> 128-edge tile, ONE block/CU but 8 waves/CU.
// LDS: 64 KB weights + 8 x 8 KB DMA row stage + 8 x 2 KB sH1 = 144 KB.
// Gather via global_load_lds: one instr = 4 complete 256B rows (16 contiguous lanes/row)
// = 8 dense 128B lines; zero staging VGPRs (the historic 512-thread spill source).
template<bool XBF>
__global__ __launch_bounds__(512, 1)
void edge_mlp_kernel(const float* __restrict__ x,
                     const unsigned short* __restrict__ xb,
                     const int* __restrict__ src,
                     const int* __restrict__ dst,
                     const float* __restrict__ W1, const float* __restrict__ b1,
                     const float* __restrict__ W2, const float* __restrict__ b2,
                     const float* __restrict__ W3, const float* __restrict__ b3,
                     float* __restrict__ out, int E, int ntiles)
{
    __shared__ short sW1[HDIM * HDIM];      // 32 KB
    __shared__ short sW2[HDIM * HDIM];      // 32 KB
    __shared__ short sStage[8][32 * 128];   // 64 KB: per-wave 32 rows (16 src + 16 dst) x 256 B
    __shared__ short sH1[8][16 * 64];       // 16 KB

    const int tid = threadIdx.x;

    // ---- stage weights fp32 [k][n] -> LDS bf16 WT[n][k], swizzled ----
    {
        const int n  = tid & 127;
        const int kh = tid >> 7;            // 0..3
        #pragma unroll
        for (int c = 0; c < 4; ++c) {
            const int kc = kh * 4 + c;      // 16B chunk index, 0..15
            const int k0 = kc * 8;
            short v1[8], v2[8];
            #pragma unroll
            for (int j = 0; j < 8; ++j) {
                v1[j] = f2bf(W1[(k0 + j) * HDIM + n]);
                v2[j] = f2bf(W2[(k0 + j) * HDIM + n]);
            }
            const int off = n * HDIM + ((kc ^ (n & 7)) << 3);
            bf16x8 t1 = { v1[0], v1[1], v1[2], v1[3], v1[4], v1[5], v1[6], v1[7] };
            bf16x8 t2 = { v2[0], v2[1], v2[2], v2[3], v2[4], v2[5], v2[6], v2[7] };
            *(bf16x8*)(sW1 + off) = t1;
            *(bf16x8*)(sW2 + off) = t2;
        }
    }
    __syncthreads();   // only barrier; stage/sH1 are wave-private

    const int w    = tid >> 6;      // wave 0..7
    const int lane = tid & 63;
    const int g    = lane >> 4;     // 16-lane group 0..3
    const int e16  = lane & 15;
    const int lhi  = lane >> 4;     // row-within-DMA-instr
    const int c16  = lane & 15;     // 16B chunk within row
    short* myH1 = &sH1[w][0];
    short* myS  = &sStage[w][0];

    float b1v[8], b2v[8], w3v[8];
    #pragma unroll
    for (int nt = 0; nt < 8; ++nt) {
        b1v[nt] = b1[nt * 16 + e16];
        b2v[nt] = b2[nt * 16 + e16];
        w3v[nt] = W3[nt * 16 + e16];
    }
    const float b3s = b3[0];

    const int G = gridDim.x;
    int tile = blockIdx.x;
    if (tile >= ntiles) return;

    // idv: lane<32 holds src id of edge (base + (lane&15)), lane>=32 holds dst id
    #define LOAD_IDS(T, OUTV) {                                   \
        int a = ((T) << 7) + (w << 4) + e16;                      \
        a = a < E ? a : 0;                                        \
        (OUTV) = (lane < 32) ? src[a] : dst[a];                   \
    }

    // 8 coalesced DMAs: instr i loads 4 rows (i<4: src edges 4i..4i+3, i>=4: dst).
    // Stage row r = edge (+16 for dst); (r&7)==(e4&7) for both halves.
    // Global chunk pre-swizzled (c16 ^ (e4&7)); LDS dest linear (rule #21).
    #define ISSUE_DMA(IDV) {                                      \
        _Pragma("unroll")                                         \
        for (int i = 0; i < 8; ++i) {                             \
            const int e4 = ((i & 3) << 2) + lhi;                  \
            const int rowlane = (i < 4) ? e4 : (32 + e4);         \
            const int rid = __builtin_amdgcn_ds_bpermute(rowlane << 2, (IDV)); \
            const int gchunk = c16 ^ (e4 & 7);                    \
            dma16(xb + (size_t)rid * HDIM + (gchunk << 3), myS + i * 512); \
        }                                                         \
    }

    int idv;
    LOAD_IDS(tile, idv);
    if constexpr (XBF) { ISSUE_DMA(idv); }
    int idvN = 0;
    if (tile + G < ntiles) LOAD_IDS(tile + G, idvN);

    for (;;) {
        const bool hasN = tile + G < ntiles;
        const int base = (tile << 7) + (w << 4);

        // ---------- GEMM1: H1 = relu((xs*xd) @ W1 + b1) ----------
        f32x4 acc[8];
        #pragma unroll
        for (int nt = 0; nt < 8; ++nt) {
            f32x4 iv = { b1v[nt], b1v[nt], b1v[nt], b1v[nt] };
            acc[nt] = iv;
        }

        if constexpr (XBF) {
            asm volatile("s_waitcnt vmcnt(0)" ::: "memory");   // this tile's DMA landed
            #pragma unroll
            for (int t = 0; t < 4; ++t) {
                const int c0 = (((t << 2) + g) ^ (e16 & 7)) << 3;
                bf16x8 vs = *(const bf16x8*)(myS + e16 * 128 + c0);
                bf16x8 vd = *(const bf16x8*)(myS + 2048 + e16 * 128 + c0);
                bf16x8 a0;
                #pragma unroll
                for (int j = 0; j < 8; ++j)
                    a0[j] = f2bf(bf2f(vs[j]) * bf2f(vd[j]));
                #pragma unroll
                for (int nt = 0; nt < 8; ++nt) {
                    bf16x8 bb = ldB(sW1, nt * 16 + e16, t * 4 + g);
                    acc[nt] = __builtin_amdgcn_mfma_f32_16x16x32_bf16(a0, bb, acc[nt], 0, 0, 0);
                }
            }
        } else {
            const int s0 = __builtin_amdgcn_ds_bpermute(e16 << 2, idv);
            const int d0 = __builtin_amdgcn_ds_bpermute((32 + e16) << 2, idv);
            const float* xs0 = x + (size_t)s0 * HDIM;
            const float* xd0 = x + (size_t)d0 * HDIM;
            #pragma unroll
            for (int t = 0; t < 4; ++t) {
                const int k0 = t * 32 + g * 8;
                bf16x8 a0 = gatherA_f32(xs0, xd0, k0);
                #pragma unroll
                for (int nt = 0; nt < 8; ++nt) {
                    bf16x8 bb = ldB(sW1, nt * 16 + e16, t * 4 + g);
                    acc[nt] = __builtin_amdgcn_mfma_f32_16x16x32_bf16(a0, bb, acc[nt], 0, 0, 0);
                }
            }
        }

        // ---------- stage free: issue next tile's DMA (lands under GEMM2+epilogue) ----------
        if constexpr (XBF) {
            if (hasN) {
                asm volatile("s_waitcnt lgkmcnt(0)" ::: "memory");  // stage reads drained
                ISSUE_DMA(idvN);
            }
        }
        int idvN2 = 0;
        if (tile + 2 * G < ntiles) LOAD_IDS(tile + 2 * G, idvN2);

        // ---------- GEMM2: H2 = relu(H1 @ W2 + b2) ----------
        f32x4 acc2[8];
        #pragma unroll
        for (int nt = 0; nt < 8; ++nt) {
            f32x4 iv = { b2v[nt], b2v[nt], b2v[nt], b2v[nt] };
            acc2[nt] = iv;
        }
        #pragma unroll
        for (int khf = 0; khf < 2; ++khf) {
            #pragma unroll
            for (int ntl = 0; ntl < 4; ++ntl) {
                const int nt = khf * 4 + ntl;
                #pragma unroll
                for (int r = 0; r < 4; ++r) {
                    const int e  = g * 4 + r;         // edge-row 0..15
                    const int kk = ntl * 16 + e16;
                    float v = acc[nt][r];
                    v = v > 0.0f ? v : 0.0f;
                    myH1[e * 64 + (((kk >> 3) ^ (e & 7)) << 3) + (kk & 7)] = f2bf(v);
                }
            }
            #pragma unroll
            for (int tl = 0; tl < 2; ++tl) {
                const int ck = tl * 4 + g;
                bf16x8 a0 = *(const bf16x8*)(myH1 + e16 * 64 + ((ck ^ (e16 & 7)) << 3));
                const int t2 = khf * 2 + tl;
                #pragma unroll
                for (int nt = 0; nt < 8; ++nt) {
                    bf16x8 bb = ldB(sW2, nt * 16 + e16, t2 * 4 + g);
                    acc2[nt] = __builtin_amdgcn_mfma_f32_16x16x32_bf16(a0, bb, acc2[nt], 0, 0, 0);
                }
            }
        }

        // ---------- final: out = relu(H2) @ W3 + b3, 16-lane butterfly ----------
        {
            float p0 = 0.f, p1 = 0.f, p2 = 0.f, p3 = 0.f;
            #pragma unroll
            for (int nt = 0; nt < 8; ++nt) {
                f32x4 v = acc2[nt];
                float r0 = v[0] > 0.f ? v[0] : 0.f;
                float r1 = v[1] > 0.f ? v[1] : 0.f;
                float r2 = v[2] > 0.f ? v[2] : 0.f;
                float r3 = v[3] > 0.f ? v[3] : 0.f;
                p0 += r0 * w3v[nt];
                p1 += r1 * w3v[nt];
                p2 += r2 * w3v[nt];
                p3 += r3 * w3v[nt];
            }
            #pragma unroll
            for (int off = 1; off < 16; off <<= 1) {
                p0 += __shfl_xor(p0, off);
                p1 += __shfl_xor(p1, off);
                p2 += __shfl_xor(p2, off);
                p3 += __shfl_xor(p3, off);
            }
            if (e16 == 0) {
                const int eb = base + g * 4;
                if (eb + 0 < E) out[eb + 0] = p0 + b3s;
                if (eb + 1 < E) out[eb + 1] = p1 + b3s;
                if (eb + 2 < E) out[eb + 2] = p2 + b3s;
                if (eb + 3 < E) out[eb + 3] = p3 + b3s;
            }
        }

        if (!hasN) break;
        tile += G;
        idv = idvN;
        idvN = idvN2;
    }
    #undef LOAD_IDS
    #undef ISSUE_DMA
}

extern "C" void kernel_launch(void* const* d_in, const int* in_sizes, int n_in,
                              void* d_out, int out_size, void* d_ws, size_t ws_size,
                              hipStream_t stream) {
    const float* x   = (const float*)d_in[0];
    const int*   src = (const int*)d_in[1];
    const int*   dst = (const int*)d_in[2];
    const float* W1  = (const float*)d_in[3];
    const float* b1  = (const float*)d_in[4];
    const float* W2  = (const float*)d_in[5];
    const float* b2  = (const float*)d_in[6];
    const float* W3  = (const float*)d_in[7];
    const float* b3  = (const float*)d_in[8];
    float* out = (float*)d_out;

    const int xelems = in_sizes[0];           // N_NODES * 128
    const int E = in_sizes[1];
    const int ntiles = (E + 127) >> 7;        // 128 edges per block-tile (8 waves x 16)
    const int grid = ntiles < 256 ? ntiles : 256;   // 1 block/CU (144 KB LDS)

    const size_t need = (size_t)xelems * sizeof(unsigned short);
    if (ws_size >= need) {
        unsigned short* xb = (unsigned short*)d_ws;
        hipLaunchKernelGGL(cvt_kernel, dim3(2048), dim3(256), 0, stream, x, xb, xelems >> 2);
        hipLaunchKernelGGL((edge_mlp_kernel<true>), dim3(grid), dim3(512), 0, stream,
                           x, xb, src, dst, W1, b1, W2, b2, W3, b3, out, E, ntiles);
    } else {
        hipLaunchKernelGGL((edge_mlp_kernel<false>), dim3(grid), dim3(512), 0, stream,
                           x, (const unsigned short*)nullptr, src, dst,
                           W1, b1, W2, b2, W3, b3, out, E, ntiles);
    }
}